// Round 12
// baseline (120.740 us; speedup 1.0000x reference)
//
#include <hip/hip_runtime.h>

#define NQ 2048
#define NO 2048
#define NOC 32   // o-chunks of 64

// ws layout (float offsets): Ph [NOC][NQ][64] (pre-Wv h partials, 17 MB),
// Ps [NOC][NQ]. Keep 17 MB (R10: bigger partials double-charge HBM vs fill).
constexpr size_t OFF_PH = 0;
constexpr size_t OFF_PS = (size_t)NOC * NQ * 64;

__device__ __forceinline__ float rfl(float x) {
    int i = __builtin_amdgcn_readfirstlane(__builtin_bit_cast(int, x));
    return __builtin_bit_cast(float, i);
}

// ---------------------------------------------------------------------------
// Main: 1024 blocks = 32 q-groups(64) x 32 o-chunks(64). lane = q.
// LDS-pipe diet (R7..R11 post-mortem: LDS pipe is CU-shared, VALU per-SIMD;
// t-tile broadcasts made every variant LDS-bound at ~272-512 ops/wave):
//   - pos_o for the wave's 16 o's -> 48 SGPRs (readfirstlane, loaded ONCE)
//   - t recomputed per (l,o): acc = u; acc = fma(D,s_po0,acc); ... (1 SGPR/fma)
//   - only hot-loop LDS: 2 broadcast b128 per l (coeff row) = 128/wave
// Phase A: wave w -> o-slice [16w,+16), lg[16]. Phase B: wave w -> l-slice
// [16w,+16), all 64 o (R11 verbatim). Two barriers; no atomics.
// ---------------------------------------------------------------------------
__global__ __launch_bounds__(256, 6) void gano_main(
    const float* __restrict__ h_obs,
    const float* __restrict__ pos_obs,
    const float* __restrict__ pos_query,
    const float* __restrict__ W1,
    const float* __restrict__ b1,
    const float* __restrict__ W2,
    float* __restrict__ Ph,
    float* __restrict__ Ps)
{
    __shared__ __align__(16) float cf[64 * 8];   // [l]{A,B,C,b1, W2,D,E,F}
    __shared__ float ue[64 * 64];                // e [o_local][q-lane]
    __shared__ float sbuf[4 * 64];

    const int tid  = threadIdx.x;
    const int lane = tid & 63;
    const int wave = __builtin_amdgcn_readfirstlane(tid >> 6);
    const int qg = blockIdx.x >> 5;   // 0..31
    const int oc = blockIdx.x & 31;   // 0..31
    const int obase = oc * 64;
    const int q  = qg * 64 + lane;
    const int ow = wave * 16;         // phase A o-slice / phase B l-slice base

    // ---- stage coeff table (first 64 threads; l = tid; once) ----
    if (tid < 64) {
        float w0 = W1[0*64+tid], w1_ = W1[1*64+tid], w2_ = W1[2*64+tid];
        float w3 = W1[3*64+tid], w4  = W1[4*64+tid], w5  = W1[5*64+tid];
        float w6 = W1[6*64+tid], w7  = W1[7*64+tid], w8  = W1[8*64+tid];
        float* r = cf + tid * 8;
        r[0] = w0 + w6;  r[1] = w1_ + w7;  r[2] = w2_ + w8;   // A,B,C (u)
        r[3] = b1[tid];  r[4] = W2[tid];
        r[5] = w3 - w6;  r[6] = w4 - w7;   r[7] = w5 - w8;    // D,E,F (t)
    }
    float pq0 = pos_query[q * 3 + 0];
    float pq1 = pos_query[q * 3 + 1];
    float pq2 = pos_query[q * 3 + 2];

    // ---- pos_o for this wave's 16 o's -> SGPRs (once; uniform s_loads) ----
    float px[16], py[16], pz[16];
    {
        const float* pob = pos_obs + __builtin_amdgcn_readfirstlane((obase + ow) * 3);
#pragma unroll
        for (int o = 0; o < 16; ++o) {
            px[o] = rfl(pob[o * 3 + 0]);
            py[o] = rfl(pob[o * 3 + 1]);
            pz[o] = rfl(pob[o * 3 + 2]);
        }
    }
    __syncthreads();   // sync0: cf visible

    // ---- Phase A: l-outer; u = 3 fma; t recomputed per (l,o) from SGPRs ----
    float lg[16];
#pragma unroll
    for (int o = 0; o < 16; ++o) lg[o] = 0.f;
#pragma unroll 4
    for (int l = 0; l < 64; ++l) {
        float4 ca = *(const float4*)(cf + l * 8);      // broadcast b128: A,B,C,b1
        float4 cb = *(const float4*)(cf + l * 8 + 4);  // broadcast b128: W2,D,E,F
        float u = fmaf(pq2, ca.z, fmaf(pq1, ca.y, fmaf(pq0, ca.x, ca.w)));
#pragma unroll
        for (int o = 0; o < 16; ++o) {
            float acc = fmaf(cb.y, px[o], u);          // D*po0 + u   (1 SGPR)
            acc = fmaf(cb.z, py[o], acc);              // +E*po1      (1 SGPR)
            acc = fmaf(cb.w, pz[o], acc);              // +F*po2      (1 SGPR)
            lg[o] = fmaf(cb.x, fmaxf(acc, 0.f), lg[o]);
        }
    }

    // ---- mask + exp; e -> LDS ----
    float spart = 0.f;
#pragma unroll
    for (int o = 0; o < 16; ++o) {
        float d0 = pq0 - px[o];
        float d1 = pq1 - py[o];
        float d2 = pq2 - pz[o];
        float dd = d0 * d0 + d1 * d1 + d2 * d2;
        float ev = (dd > 0.25f) ? 0.f : __expf(lg[o]);   // logits O(1): raw exp safe
        spart += ev;
        ue[(ow + o) * 64 + lane] = ev;                   // 2-way bank = free
    }
    sbuf[wave * 64 + lane] = spart;
    __syncthreads();   // sync1: e-buffer ready

    // ---- Phase B (R11 verbatim): wave w -> l-slice [ow,+16), all 64 o ----
    float h0 = 0.f, h1 = 0.f, h2 = 0.f, h3 = 0.f, h4 = 0.f, h5 = 0.f, h6 = 0.f, h7 = 0.f;
    float h8 = 0.f, h9 = 0.f, hA = 0.f, hB = 0.f, hC = 0.f, hD = 0.f, hE = 0.f, hF = 0.f;
#pragma unroll 4
    for (int o = 0; o < 64; ++o) {
        float eo = ue[o * 64 + lane];                    // b32, 2-way = free
        const float4* hr = (const float4*)(h_obs + (size_t)(obase + o) * 64 + ow); // uniform
        float4 v0 = hr[0], v1 = hr[1], v2 = hr[2], v3 = hr[3];
        h0 += eo * v0.x; h1 += eo * v0.y; h2 += eo * v0.z; h3 += eo * v0.w;
        h4 += eo * v1.x; h5 += eo * v1.y; h6 += eo * v1.z; h7 += eo * v1.w;
        h8 += eo * v2.x; h9 += eo * v2.y; hA += eo * v2.z; hB += eo * v2.w;
        hC += eo * v3.x; hD += eo * v3.y; hE += eo * v3.z; hF += eo * v3.w;
    }

    // ---- stores: disjoint per wave, float4 ----
    float* hp = Ph + ((size_t)oc * NQ + (size_t)qg * 64 + lane) * 64 + ow;
    ((float4*)hp)[0] = make_float4(h0, h1, h2, h3);
    ((float4*)hp)[1] = make_float4(h4, h5, h6, h7);
    ((float4*)hp)[2] = make_float4(h8, h9, hA, hB);
    ((float4*)hp)[3] = make_float4(hC, hD, hE, hF);
    if (wave == 0) {
        float s = sbuf[lane] + sbuf[64 + lane] + sbuf[128 + lane] + sbuf[192 + lane];
        Ps[(size_t)oc * NQ + (size_t)qg * 64 + lane] = s;
    }
}

// ---------------------------------------------------------------------------
// Combine + Wv projection (R7-measured): g[q][k] = sum_c Ph[c][q][k];
// s = sum_c Ps[c][q]; out[q][l] = (g[q][:]/s) @ Wv + bv.  512 blocks.
// ---------------------------------------------------------------------------
__global__ __launch_bounds__(256, 2) void gano_comb(
    const float* __restrict__ Ph,
    const float* __restrict__ Ps,
    const float* __restrict__ Wv,
    const float* __restrict__ bv,
    float* __restrict__ out)
{
    __shared__ __align__(16) float wv[64 * 64];
    __shared__ __align__(16) float g[4 * 68];
    const int tid  = threadIdx.x;
    const int lane = tid & 63;
    const int wave = tid >> 6;
    const int q0 = blockIdx.x * 4;
    {
        const float4* src = (const float4*)Wv;
        float4* dst = (float4*)wv;
#pragma unroll
        for (int k = 0; k < 4; ++k) dst[tid + k * 256] = src[tid + k * 256];
    }
    {
        const int qi = wave, k = lane;
        float acc = 0.f;
#pragma unroll
        for (int c = 0; c < NOC; ++c)
            acc += Ph[((size_t)c * NQ + q0 + qi) * 64 + k];
        g[qi * 68 + k] = acc;
        if (k == 0) {
            float ss = 0.f;
#pragma unroll
            for (int c = 0; c < NOC; ++c) ss += Ps[(size_t)c * NQ + q0 + qi];
            g[qi * 68 + 64] = ss;
        }
    }
    __syncthreads();
    const float* gq = g + wave * 68;            // wave-uniform broadcast
    float inv = 1.0f / gq[64];
    float a0 = 0.f, a1 = 0.f, a2 = 0.f, a3 = 0.f;
#pragma unroll
    for (int kb = 0; kb < 16; ++kb) {
        float4 g4 = *(const float4*)(gq + kb * 4);
        a0 += g4.x * wv[(kb * 4 + 0) * 64 + lane];
        a1 += g4.y * wv[(kb * 4 + 1) * 64 + lane];
        a2 += g4.z * wv[(kb * 4 + 2) * 64 + lane];
        a3 += g4.w * wv[(kb * 4 + 3) * 64 + lane];
    }
    out[(size_t)(q0 + wave) * 64 + lane] = ((a0 + a1) + (a2 + a3)) * inv + bv[lane];
}

// ---------------------------------------------------------------------------
extern "C" void kernel_launch(void* const* d_in, const int* in_sizes, int n_in,
                              void* d_out, int out_size, void* d_ws, size_t ws_size,
                              hipStream_t stream) {
    const float* h_obs     = (const float*)d_in[0];
    // d_in[1] = x_obs (unused by reference)
    const float* pos_obs   = (const float*)d_in[2];
    const float* pos_query = (const float*)d_in[3];
    const float* W1        = (const float*)d_in[4];
    const float* b1        = (const float*)d_in[5];
    const float* W2        = (const float*)d_in[6];
    // d_in[7] = b2: constant shift, cancels in softmax
    const float* Wv        = (const float*)d_in[8];
    const float* bv        = (const float*)d_in[9];
    float* ws  = (float*)d_ws;
    float* out = (float*)d_out;

    gano_main<<<dim3(1024), dim3(256), 0, stream>>>(h_obs, pos_obs, pos_query,
                                                    W1, b1, W2, ws + OFF_PH, ws + OFF_PS);
    gano_comb<<<dim3(NQ / 4), dim3(256), 0, stream>>>(ws + OFF_PH, ws + OFF_PS, Wv, bv, out);
}